// Round 8
// baseline (1412.059 us; speedup 1.0000x reference)
//
#include <hip/hip_runtime.h>

#define B_TOT   512
#define T_LEN   512
#define F_IN_D  8
#define H_DIM   128
#define OUT_DIM 7
#define TC      8                 // timesteps per chunk
#define NCHUNK  (T_LEN / TC)      // 64
#define BB      2                 // batch rows per block
#define NBLK    (B_TOT / BB)      // 256 blocks -> 1 per CU
#define NTHREADS 512              // 8 waves
#define XG_PLANE 516              // f32 words per (2*trel+b) plane; 516%32=4 -> 2-way max

typedef __bf16 bf16x8 __attribute__((ext_vector_type(8)));
typedef float  f32x4  __attribute__((ext_vector_type(4)));

struct __align__(16) SharedMem {
  float  xg[2 * TC][XG_PLANE];  // [2*trel+b][wave*64 + (4i+q)*4 + r] permuted xg (33 KB)
  float  gx[8][2][18][4];       // wave-private gate exchange [w][b][slot(pad 18)][gate]
  float  z[2][H_DIM];           // fc1 output
  __bf16 h[2][2][160];          // [parity][b][k]; stride 160 -> b=1 is +16 banks
  __bf16 hist[TC][2][H_DIM];    // chunk h history -> ONE coalesced global store per chunk
};

__device__ __forceinline__ float sigf(float x) {
  return __builtin_amdgcn_rcpf(1.f + __expf(-x));
}
__device__ __forceinline__ float tanh_fast(float x) {
  x = fminf(fmaxf(x, -15.f), 15.f);
  float e = __expf(2.f * x);
  return (e - 1.f) * __builtin_amdgcn_rcpf(e + 1.f);
}
__device__ __forceinline__ bf16x8 load8_f32_bf16(const float* p) {
  const f32x4 a = *(const f32x4*)p;
  const f32x4 b = *(const f32x4*)(p + 4);
  bf16x8 r;
  #pragma unroll
  for (int j = 0; j < 4; ++j) { r[j] = (__bf16)a[j]; r[4 + j] = (__bf16)b[j]; }
  return r;
}
__device__ __forceinline__ bf16x8 zero_bf16x8() {
  bf16x8 r;
  #pragma unroll
  for (int j = 0; j < 8; ++j) r[j] = (__bf16)0.f;
  return r;
}

// R6 frame + gate-row permutation. MFMA row P = 16*mt+u (mt = w+8i) maps to
// original W row orig(P) = 128*(u&3) + 32*i + 4*w + (u>>2). With C/D mapping
// row = 4q+reg, col = n16: acc[i][r] = gate r (i,f,g,o) of j = 4w+q+32i, batch = n16.
// => masked lanes hand off gates as raw b128 stores (no transpose); gate lanes
// read ONE b128. One __syncthreads per step (h visibility only).
__global__ __launch_bounds__(NTHREADS, 2)
void lstm_kernel(const float* __restrict__ x,
                 const float* __restrict__ wih0, const float* __restrict__ whh0,
                 const float* __restrict__ bih0, const float* __restrict__ bhh0,
                 const float* __restrict__ wih1, const float* __restrict__ whh1,
                 const float* __restrict__ bih1, const float* __restrict__ bhh1,
                 const float* __restrict__ wih2, const float* __restrict__ whh2,
                 const float* __restrict__ bih2, const float* __restrict__ bhh2,
                 const float* __restrict__ fc1w, const float* __restrict__ fc1b,
                 const float* __restrict__ fc2w, const float* __restrict__ fc2b,
                 float* __restrict__ out, __bf16* __restrict__ buf)
{
  __shared__ SharedMem sh;
  const int tid = threadIdx.x;
  const int w   = tid >> 6;   // wave 0..7
  const int l   = tid & 63;   // lane
  const int q   = l >> 4;     // quad 0..3
  const int n16 = l & 15;     // MFMA col = batch slot (0,1 real)
  const int bg  = blockIdx.x * BB;

  // gate-lane constants (lanes l<32): one (b, j) each
  const int gb  = l >> 4;               // 0/1 for l<32
  const int gji = l & 15;               // slot
  const int gj  = 4 * w + (gji & 3) + 32 * (gji >> 2);

  const float* WIH[3] = {wih0, wih1, wih2};
  const float* WHH[3] = {whh0, whh1, whh2};
  const float* BIH[3] = {bih0, bih1, bih2};
  const float* BHH[3] = {bhh0, bhh1, bhh2};

  for (int lyr = 0; lyr < 3; ++lyr) {
    const float* w_ih = WIH[lyr];
    const float* w_hh = WHH[lyr];
    const float* b_ih = BIH[lyr];
    const float* b_hh = BHH[lyr];
    const int kin        = (lyr == 0) ? F_IN_D : H_DIM;
    const int kin_chunks = (lyr == 0) ? 1 : 4;

    // ---- per-layer resident A-fragments (PERMUTED rows) + bias C-init ----
    bf16x8 whhf[4][4];   // [tile][kchunk]
    bf16x8 wihf[4][4];
    f32x4  biasv[4];
    #pragma unroll
    for (int i = 0; i < 4; ++i) {
      const int u  = n16;
      const int ro = ((u & 3) << 7) + (i << 5) + (w << 2) + (u >> 2);  // orig row
      #pragma unroll
      for (int kc = 0; kc < 4; ++kc) {
        whhf[i][kc] = load8_f32_bf16(w_hh + ro * H_DIM + kc * 32 + q * 8);
        const int k0 = kc * 32 + q * 8;
        wihf[i][kc] = (k0 < kin) ? load8_f32_bf16(w_ih + ro * kin + k0)
                                 : zero_bf16x8();
      }
      const int jj = 4 * w + q + 32 * i;
      f32x4 bv;
      #pragma unroll
      for (int r = 0; r < 4; ++r) bv[r] = b_ih[(r << 7) + jj] + b_hh[(r << 7) + jj];
      biasv[i] = bv;
    }

    if (tid < 2 * H_DIM) sh.h[0][tid >> 7][tid & 127] = (__bf16)0.f;
    float c_st = 0.f;   // cell state for gate lane (gb, gj)
    __syncthreads();    // h reset visible; orders prev-layer buf flush vs prologue reads

    float* const xw = &sh.xg[0][0] + n16 * XG_PLANE + 64 * w + 4 * q;        // store base
    float* const xr = &sh.xg[0][0] + (n16 & 1) * XG_PLANE + 64 * w + 4 * q;  // read base

    for (int c0 = 0; c0 < NCHUNK; ++c0) {
      const int t0 = c0 * TC;

      // ---- flush previous chunk's hist -> buf (coalesced; drains off-path) ----
      if (lyr < 2 && c0 > 0 && tid < 256) {
        const int s2 = tid >> 5, rem = tid & 31;
        const int b2 = rem >> 4, k8 = (rem & 15) * 8;
        const bf16x8 v = *(const bf16x8*)&sh.hist[s2][b2][k8];
        *(bf16x8*)(buf + ((size_t)(bg + b2) * T_LEN + (t0 - TC) + s2) * H_DIM + k8) = v;
      }

      // ---- prologue: xg for TC steps; col n16 = (trel, b). Wave-private -> no barrier ----
      {
        f32x4 acc[4];
        #pragma unroll
        for (int i = 0; i < 4; ++i) acc[i] = biasv[i];
        const int bb   = n16 & 1;
        const int trel = n16 >> 1;
        const int t    = t0 + trel;
        #pragma unroll
        for (int kc = 0; kc < 4; ++kc) {
          if (kc < kin_chunks) {            // wave-uniform guard
            bf16x8 bfrag;
            if (lyr == 0) {
              bfrag = zero_bf16x8();
              if (q == 0)
                bfrag = load8_f32_bf16(x + ((size_t)(bg + bb) * T_LEN + t) * F_IN_D);
            } else {
              bfrag = *(const bf16x8*)(buf + ((size_t)(bg + bb) * T_LEN + t) * H_DIM
                                           + kc * 32 + q * 8);
            }
            #pragma unroll
            for (int i = 0; i < 4; ++i)
              acc[i] = __builtin_amdgcn_mfma_f32_16x16x32_bf16(
                  wihf[i][kc], bfrag, acc[i], 0, 0, 0);
          }
        }
        #pragma unroll
        for (int i = 0; i < 4; ++i)
          *(f32x4*)(xw + 16 * i) = acc[i];   // plane n16, wave-private slots
      }

      // ---- TC steps, fully unrolled (immediate LDS offsets), ONE barrier each ----
      #pragma unroll
      for (int s = 0; s < TC; ++s) {
        const int cur = s & 1, nxt = cur ^ 1;   // t parity == s parity

        f32x4 acc[4];
        #pragma unroll
        for (int i = 0; i < 4; ++i)             // C-init = xg (wave-private read)
          acc[i] = *(const f32x4*)(xr + 2 * s * XG_PLANE + 16 * i);
        #pragma unroll
        for (int kc = 0; kc < 4; ++kc) {
          const bf16x8 bfrag = *(const bf16x8*)&sh.h[cur][n16 & 1][kc * 32 + q * 8];
          #pragma unroll
          for (int i = 0; i < 4; ++i)
            acc[i] = __builtin_amdgcn_mfma_f32_16x16x32_bf16(
                whhf[i][kc], bfrag, acc[i], 0, 0, 0);
        }

        // gate handoff: raw b128 stores, NO transpose (acc[i] = 4 gates of one j)
        if (n16 < 2) {
          #pragma unroll
          for (int i = 0; i < 4; ++i)
            *(f32x4*)&sh.gx[w][n16][4 * i + q][0] = acc[i];
        }
        __builtin_amdgcn_wave_barrier();   // DS pipe in-order within wave (R7-validated)

        if (l < 32) {                      // dense gate math: one (b,j) per lane
          const f32x4 g = *(const f32x4*)&sh.gx[w][gb][gji][0];
          c_st = sigf(g[1]) * c_st + sigf(g[0]) * tanh_fast(g[2]);
          const __bf16 hb = (__bf16)(sigf(g[3]) * tanh_fast(c_st));
          sh.h[nxt][gb][gj]  = hb;         // broadcast for t+1
          sh.hist[s][gb][gj] = hb;         // batched flush next chunk
        }
        __syncthreads();                   // h visible to all waves for step s+1
      }
    }

    // ---- flush the last chunk of this layer ----
    if (lyr < 2 && tid < 256) {
      const int s2 = tid >> 5, rem = tid & 31;
      const int b2 = rem >> 4, k8 = (rem & 15) * 8;
      const bf16x8 v = *(const bf16x8*)&sh.hist[s2][b2][k8];
      *(bf16x8*)(buf + ((size_t)(bg + b2) * T_LEN + (T_LEN - TC) + s2) * H_DIM + k8) = v;
    }
  }

  // ---- FC head: final h of layer 2 (t=511 wrote parity 0) ----
  if (tid < 2 * H_DIM) {
    const int bb = tid >> 7, i = tid & 127;
    float a = fc1b[i];
    #pragma unroll 8
    for (int k = 0; k < H_DIM; ++k)
      a += (float)sh.h[0][bb][k] * fc1w[i * H_DIM + k];
    sh.z[bb][i] = fmaxf(a, 0.f);
  }
  __syncthreads();
  if (tid < BB * OUT_DIM) {
    const int bb = tid / OUT_DIM, o = tid % OUT_DIM;
    float a = fc2b[o];
    for (int k = 0; k < H_DIM; ++k)
      a += sh.z[bb][k] * fc2w[o * H_DIM + k];
    out[(size_t)(bg + bb) * OUT_DIM + o] = a;
  }
}

extern "C" void kernel_launch(void* const* d_in, const int* in_sizes, int n_in,
                              void* d_out, int out_size, void* d_ws, size_t ws_size,
                              hipStream_t stream) {
  const float* x    = (const float*)d_in[0];
  const float* wih0 = (const float*)d_in[1];
  const float* whh0 = (const float*)d_in[2];
  const float* bih0 = (const float*)d_in[3];
  const float* bhh0 = (const float*)d_in[4];
  const float* wih1 = (const float*)d_in[5];
  const float* whh1 = (const float*)d_in[6];
  const float* bih1 = (const float*)d_in[7];
  const float* bhh1 = (const float*)d_in[8];
  const float* wih2 = (const float*)d_in[9];
  const float* whh2 = (const float*)d_in[10];
  const float* bih2 = (const float*)d_in[11];
  const float* bhh2 = (const float*)d_in[12];
  const float* fc1w = (const float*)d_in[13];
  const float* fc1b = (const float*)d_in[14];
  const float* fc2w = (const float*)d_in[15];
  const float* fc2b = (const float*)d_in[16];
  float* out  = (float*)d_out;
  __bf16* buf = (__bf16*)d_ws;   // [512][512][128] bf16 = 64 MiB inter-layer buffer

  lstm_kernel<<<dim3(NBLK), dim3(NTHREADS), 0, stream>>>(
      x, wih0, whh0, bih0, bhh0, wih1, whh1, bih1, bhh1,
      wih2, whh2, bih2, bhh2, fc1w, fc1b, fc2w, fc2b, out, buf);
}